// Round 4
// baseline (188.657 us; speedup 1.0000x reference)
//
#include <hip/hip_runtime.h>
#include <cstdint>

// Chamfer distance, B=8, N=M=4096, D=128, f32 in, scalar f32 out.
// R4: hardware XCD-affinity. R3's blockIdx%8 heuristic failed (FETCH_SIZE
// stayed 218MB). Now each block reads its physical XCC_ID via s_getreg and
// claims work from a per-XCD atomic queue (queue q == batch q, 128 items),
// stealing from neighbors on overflow. Per-XCD footprint = 2MB < 4MB L2, so
// the 256MB y-restream becomes L2 hits regardless of dispatch mapping.
// Workspace: xb(8MiB) yb(8MiB) x2(128KiB) y2(128KiB) rowmin(128KiB)
//            colmin(128KiB) partial(512B) ctr(64B).

#define B_   8
#define N_   4096
#define M_   4096
#define D_   128
#define LDP  136   // padded LDS row stride in bf16 elems (272B: 16B-aligned, rotates banks 4/row)
#define TPB  8     // y-tiles per block
#define CHUNKS (M_ / 128 / TPB)   // 4

typedef __bf16 bf16x8 __attribute__((ext_vector_type(8)));
typedef float  f32x4  __attribute__((ext_vector_type(4)));

static __device__ __forceinline__ unsigned short f2bf(float f) {
  unsigned u = __float_as_uint(f);
  u += 0x7FFFu + ((u >> 16) & 1u);   // round-to-nearest-even
  return (unsigned short)(u >> 16);
}

// Pass 1: one wave per row. xb = bf16(-2x) (exact scale), yb = bf16(y),
// fp32 norms from the original f32 data, min arrays init to +inf bits.
__global__ __launch_bounds__(256) void pass1_prep(
    const float* __restrict__ x, const float* __restrict__ y,
    unsigned short* __restrict__ xb, unsigned short* __restrict__ yb,
    float* __restrict__ x2, float* __restrict__ y2,
    unsigned* __restrict__ rowmin, unsigned* __restrict__ colmin)
{
  const int ROWS = B_ * N_;
  int gw   = (blockIdx.x * 256 + threadIdx.x) >> 6;
  int lane = threadIdx.x & 63;
  bool isx = gw < ROWS;
  const float* src; unsigned short* dst; float* nrm; unsigned* mn; int row;
  if (isx) { src = x; dst = xb; nrm = x2; mn = rowmin; row = gw; }
  else     { src = y; dst = yb; nrm = y2; mn = colmin; row = gw - ROWS; }
  size_t base = (size_t)row * D_ + lane * 2;
  float2 v = *(const float2*)(src + base);
  float sx = isx ? -2.0f : 1.0f;
  unsigned packed = (unsigned)f2bf(sx * v.x) | ((unsigned)f2bf(sx * v.y) << 16);
  *(unsigned*)(dst + base) = packed;
  float s = v.x * v.x + v.y * v.y;
  #pragma unroll
  for (int m = 1; m < 64; m <<= 1) s += __shfl_xor(s, m, 64);
  if (lane == 0) { nrm[row] = s; mn[row] = 0x7F800000u; }
}

// Pass 2: block = 128 x-rows (4 waves x 32 rows), loops over TPB y-tiles of
// 128 cols. 16x16x32 bf16 MFMA. Fragment layouts (HW-verified):
//   A/B operand: lane holds elems [row=lane&15][k=(lane>>4)*8 + 0..7]
//   C/D:         lane reg r holds [row=(lane>>4)*4+r][col=lane&15]
// acc init = x2_row, so acc_final = x2_i - 2<x_i,y_j>; add y2_j -> d^2.
// Work claimed from per-XCD queues keyed by physical XCC_ID.
__global__ __launch_bounds__(256, 4) void pass2_tile(
    const unsigned short* __restrict__ xb, const unsigned short* __restrict__ yb,
    const float* __restrict__ x2, const float* __restrict__ y2,
    unsigned* __restrict__ rowmin, unsigned* __restrict__ colmin,
    int* __restrict__ ctr)
{
  __shared__ alignas(16) unsigned short ys[128 * LDP];
  __shared__ float y2s[128];
  __shared__ unsigned cminS[128];
  __shared__ int workItem;

  const int tid  = threadIdx.x;

  // --- Claim a work item with XCD affinity (queue q holds batch q's 128
  // tiles). Overflow-steal guarantees full coverage: counter[q] hands out
  // slots 0..127 exactly once; a block only stops after claiming one. ---
  if (tid == 0) {
    unsigned xcc;
    asm volatile("s_getreg_b32 %0, hwreg(HW_REG_XCC_ID)" : "=s"(xcc));
    int q = (int)(xcc & 7u);
    int item = -1;
    while (item < 0) {
      int slot = atomicAdd(&ctr[q], 1);
      if (slot < 128) item = q * 128 + slot;
      else q = (q + 1) & 7;
    }
    workItem = item;
  }
  if (tid < 128) cminS[tid] = 0x7F800000u;
  __syncthreads();

  const int it  = workItem;
  const int b   = it >> 7;                    // batch == home XCD (usually)
  const int j   = it & 127;
  const int n0  = (j & 31) * 128;             // x-tile
  const int mc0 = (j >> 5) * (TPB * 128);     // y-chunk

  const int wave = tid >> 6;
  const int lane = tid & 63;
  const int quad = lane >> 4;
  const int l15  = lane & 15;
  const int rowbase = wave * 32;

  // --- Stage x-tile into the (shared) buffer once, pull A-frags to regs ---
  const size_t xbase = ((size_t)b * N_ + n0) * D_;
  #pragma unroll
  for (int i = 0; i < 8; ++i) {
    int idx = i * 256 + tid;
    int r = idx >> 4;
    int c = (idx & 15) << 3;
    *(uint4*)(ys + r * LDP + c) = *(const uint4*)(xb + xbase + r * D_ + c);
  }
  __syncthreads();

  bf16x8 afrag[4][2];
  #pragma unroll
  for (int kb = 0; kb < 4; ++kb) {
    const int koff = kb * 32 + quad * 8;
    afrag[kb][0] = *(const bf16x8*)(ys + (rowbase      + l15) * LDP + koff);
    afrag[kb][1] = *(const bf16x8*)(ys + (rowbase + 16 + l15) * LDP + koff);
  }
  float xv[2][4];
  #pragma unroll
  for (int rt = 0; rt < 2; ++rt)
    #pragma unroll
    for (int r = 0; r < 4; ++r)
      xv[rt][r] = x2[(size_t)b * N_ + n0 + rowbase + rt * 16 + quad * 4 + r];

  const float FINF = __uint_as_float(0x7F800000u);
  float rmin2[2][4];
  #pragma unroll
  for (int rt = 0; rt < 2; ++rt)
    #pragma unroll
    for (int r = 0; r < 4; ++r) rmin2[rt][r] = FINF;

  __syncthreads();  // all waves finished reading x-tile; buffer now free for y

  #pragma unroll 1
  for (int t = 0; t < TPB; ++t) {
    const int m0 = mc0 + t * 128;
    const size_t ybase = ((size_t)b * M_ + m0) * D_;
    #pragma unroll
    for (int i = 0; i < 8; ++i) {
      int idx = i * 256 + tid;
      int r = idx >> 4;
      int c = (idx & 15) << 3;
      *(uint4*)(ys + r * LDP + c) = *(const uint4*)(yb + ybase + r * D_ + c);
    }
    if (tid < 128) y2s[tid] = y2[(size_t)b * M_ + m0 + tid];
    __syncthreads();

    f32x4 acc[2][8];
    #pragma unroll
    for (int rt = 0; rt < 2; ++rt)
      #pragma unroll
      for (int ct = 0; ct < 8; ++ct) {
        acc[rt][ct][0] = xv[rt][0];
        acc[rt][ct][1] = xv[rt][1];
        acc[rt][ct][2] = xv[rt][2];
        acc[rt][ct][3] = xv[rt][3];
      }

    #pragma unroll
    for (int kb = 0; kb < 4; ++kb) {
      const int koff = kb * 32 + quad * 8;
      #pragma unroll
      for (int ct = 0; ct < 8; ++ct) {
        bf16x8 bfr = *(const bf16x8*)(ys + (ct * 16 + l15) * LDP + koff);
        acc[0][ct] = __builtin_amdgcn_mfma_f32_16x16x32_bf16(afrag[kb][0], bfr, acc[0][ct], 0, 0, 0);
        acc[1][ct] = __builtin_amdgcn_mfma_f32_16x16x32_bf16(afrag[kb][1], bfr, acc[1][ct], 0, 0, 0);
      }
    }

    // Epilogue on d^2: s = acc + y2_j; track row-min and col-min.
    #pragma unroll
    for (int ct = 0; ct < 8; ++ct) {
      float yv = y2s[ct * 16 + l15];
      float cm = FINF;
      #pragma unroll
      for (int rt = 0; rt < 2; ++rt) {
        #pragma unroll
        for (int r = 0; r < 4; ++r) {
          float s = acc[rt][ct][r] + yv;
          rmin2[rt][r] = fminf(rmin2[rt][r], s);
          cm = fminf(cm, s);
        }
      }
      // col-min: reduce across quads (rows) in-wave, then LDS combine
      cm = fminf(cm, __shfl_xor(cm, 16, 64));
      cm = fminf(cm, __shfl_xor(cm, 32, 64));
      if (lane < 16) atomicMin(&cminS[ct * 16 + lane], __float_as_uint(cm));
    }
    __syncthreads();

    if (tid < 128) {
      unsigned v = cminS[tid];
      atomicMin(colmin + (size_t)b * M_ + m0 + tid, v);
      cminS[tid] = 0x7F800000u;   // re-init for next tile (safe: fenced by next barrier)
    }
  }

  // Row mins: reduce across the 16 lanes of each quad (cols), one atomic/row.
  #pragma unroll
  for (int rt = 0; rt < 2; ++rt) {
    #pragma unroll
    for (int r = 0; r < 4; ++r) {
      float v = rmin2[rt][r];
      v = fminf(v, __shfl_xor(v, 1, 64));
      v = fminf(v, __shfl_xor(v, 2, 64));
      v = fminf(v, __shfl_xor(v, 4, 64));
      v = fminf(v, __shfl_xor(v, 8, 64));
      if (l15 == 0) {
        int row = rowbase + rt * 16 + quad * 4 + r;
        atomicMin(rowmin + (size_t)b * N_ + n0 + row, __float_as_uint(v));
      }
    }
  }
}

// Pass 3: partial sums of sqrt(max(min_d2,0)) (64 blocks).
__global__ __launch_bounds__(256) void pass3_partial(
    const unsigned* __restrict__ rowmin, const unsigned* __restrict__ colmin,
    float* __restrict__ partial)
{
  float s1 = 0.0f, s2 = 0.0f;
  for (int i = blockIdx.x * 256 + threadIdx.x; i < B_ * N_; i += 64 * 256) {
    s1 += sqrtf(fmaxf(__uint_as_float(rowmin[i]), 0.0f));
    s2 += sqrtf(fmaxf(__uint_as_float(colmin[i]), 0.0f));
  }
  #pragma unroll
  for (int m = 1; m < 64; m <<= 1) { s1 += __shfl_xor(s1, m, 64); s2 += __shfl_xor(s2, m, 64); }
  __shared__ float r1[4], r2[4];
  int wave = threadIdx.x >> 6, lane = threadIdx.x & 63;
  if (lane == 0) { r1[wave] = s1; r2[wave] = s2; }
  __syncthreads();
  if (threadIdx.x == 0) {
    partial[blockIdx.x]      = r1[0] + r1[1] + r1[2] + r1[3];
    partial[64 + blockIdx.x] = r2[0] + r2[1] + r2[2] + r2[3];
  }
}

// Pass 4: final 64->1 reduce, write scalar loss.
__global__ void pass4_final(const float* __restrict__ partial, float* __restrict__ out)
{
  int lane = threadIdx.x;
  float s = partial[lane] + partial[64 + lane];
  #pragma unroll
  for (int m = 1; m < 64; m <<= 1) s += __shfl_xor(s, m, 64);
  if (lane == 0) out[0] = s / (float)(B_ * N_);
}

extern "C" void kernel_launch(void* const* d_in, const int* in_sizes, int n_in,
                              void* d_out, int out_size, void* d_ws, size_t ws_size,
                              hipStream_t stream)
{
  const float* x = (const float*)d_in[0];
  const float* y = (const float*)d_in[1];
  char* ws = (char*)d_ws;

  unsigned short* xb = (unsigned short*)(ws);
  unsigned short* yb = (unsigned short*)(ws + (8u << 20));
  float*    x2     = (float*)   (ws + (16u << 20));
  float*    y2     = (float*)   (ws + (16u << 20) + (1u << 17));
  unsigned* rowmin = (unsigned*)(ws + (16u << 20) + (2u << 17));
  unsigned* colmin = (unsigned*)(ws + (16u << 20) + (3u << 17));
  float*    partial= (float*)   (ws + (16u << 20) + (4u << 17));
  int*      ctr    = (int*)     (ws + (16u << 20) + (5u << 17));
  float* outf = (float*)d_out;

  hipMemsetAsync(ctr, 0, 64, stream);  // zero the 8 XCD work-queue counters

  pass1_prep<<<(2 * B_ * N_) / 4, 256, 0, stream>>>(x, y, xb, yb, x2, y2, rowmin, colmin);

  pass2_tile<<<(N_ / 128) * CHUNKS * B_, 256, 0, stream>>>(xb, yb, x2, y2, rowmin, colmin, ctr);

  pass3_partial<<<64, 256, 0, stream>>>(rowmin, colmin, partial);
  pass4_final<<<1, 64, 0, stream>>>(partial, outf);
}

// Round 5
// 175.379 us; speedup vs baseline: 1.0757x; 1.0757x over previous
//
#include <hip/hip_runtime.h>
#include <cstdint>

// Chamfer distance, B=8, N=M=4096, D=128, f32 in, scalar f32 out.
// R5: demand reduction. 512 x-rows/block (16 waves), y-restream 295->65 MB;
// A-fragments direct global->register (no x LDS); y staged via async
// global_load_lds (16B) into XOR-16-swizzled double-buffered LDS; all global
// atomics replaced by plain partial stores reduced in pass3.
// Workspace: xb(8M) yb(8M) x2(128K) y2(128K) rowpart(512K) colpart(1M) partial.

#define B_   8
#define N_   4096
#define M_   4096
#define D_   128
#define TPB  8               // y-tiles (128 cols) per block
#define ROWS_PB 512          // x-rows per block = 16 waves * 32
#define XG   (N_ / ROWS_PB)  // 8 x-groups
#define CHUNKS (M_ / (TPB * 128))  // 4 y-chunks

typedef __bf16 bf16x8 __attribute__((ext_vector_type(8)));
typedef float  f32x4  __attribute__((ext_vector_type(4)));
typedef unsigned int u32;

static __device__ __forceinline__ unsigned short f2bf(float f) {
  unsigned u = __float_as_uint(f);
  u += 0x7FFFu + ((u >> 16) & 1u);   // round-to-nearest-even
  return (unsigned short)(u >> 16);
}

static __device__ __forceinline__ void gld16(void* lds, const void* g) {
  __builtin_amdgcn_global_load_lds(
      (const __attribute__((address_space(1))) void*)g,
      (__attribute__((address_space(3))) void*)lds, 16, 0, 0);
}

// Pass 1: wave handles 2 rows (32 lanes x float4 each). xb = bf16(-2x),
// yb = bf16(y), fp32 norms. No min-array init needed (partials replace it).
__global__ __launch_bounds__(256) void pass1_prep(
    const float* __restrict__ x, const float* __restrict__ y,
    unsigned short* __restrict__ xb, unsigned short* __restrict__ yb,
    float* __restrict__ x2, float* __restrict__ y2)
{
  const int ROWS = B_ * N_;
  int gw   = (blockIdx.x * 256 + threadIdx.x) >> 6;   // wave id
  int lane = threadIdx.x & 63;
  int half = lane >> 5, sub = lane & 31;
  int row2 = gw * 2 + half;                  // 0 .. 2*ROWS-1 (x rows then y rows)
  bool isx = row2 < ROWS;
  const float* src; unsigned short* dst; float* nrm; int row;
  if (isx) { src = x; dst = xb; nrm = x2; row = row2; }
  else     { src = y; dst = yb; nrm = y2; row = row2 - ROWS; }
  size_t base = (size_t)row * D_ + sub * 4;
  float4 v = *(const float4*)(src + base);
  float sx = isx ? -2.0f : 1.0f;
  u32 p0 = (u32)f2bf(sx * v.x) | ((u32)f2bf(sx * v.y) << 16);
  u32 p1 = (u32)f2bf(sx * v.z) | ((u32)f2bf(sx * v.w) << 16);
  *(uint2*)(dst + base) = make_uint2(p0, p1);
  float s = v.x * v.x + v.y * v.y + v.z * v.z + v.w * v.w;
  #pragma unroll
  for (int m = 1; m < 32; m <<= 1) s += __shfl_xor(s, m, 64);
  if (sub == 0) nrm[row] = s;
}

// Pass 2: block = 512 x-rows (16 waves x 32), loops over TPB y-tiles of 128
// cols. y staged by global_load_lds into XOR-swizzled LDS (row r, logical
// 16B-chunk c stored at physical chunk c^(r&15); rows 256 B, no padding).
// Fragment layouts (HW-verified):
//   A/B operand: lane holds elems [row=lane&15][k=(lane>>4)*8 + 0..7]
//   C/D:         lane reg r holds [row=(lane>>4)*4+r][col=lane&15]
// acc = -2<x,y>; epilogue s = acc + x2_i + y2_j = d^2; mins on d^2.
__global__ __launch_bounds__(1024, 4) void pass2_tile(
    const unsigned short* __restrict__ xb, const unsigned short* __restrict__ yb,
    const float* __restrict__ x2, const float* __restrict__ y2,
    float* __restrict__ rowpart, float* __restrict__ colpart)
{
  __shared__ unsigned short ys[2 * 16384];   // two 32 KB swizzled y-tiles
  __shared__ float cminW[16 * 128];          // per-wave col mins

  const int tid  = threadIdx.x;
  const int wave = tid >> 6;
  const int lane = tid & 63;
  const int quad = lane >> 4;
  const int l15  = lane & 15;

  const int id    = blockIdx.x;        // 0..255
  const int b     = id & 7;
  const int j     = id >> 3;           // 0..31
  const int xg    = j & 7;
  const int chunk = j >> 3;            // 0..3
  const int n0    = xg * ROWS_PB;
  const int mc0   = chunk * (TPB * 128);

  // DMA lane offsets: instr i of wave w covers tile bytes (w*2+i)*1024+lane*16.
  int srcoff[2], ldsoff[2];
  #pragma unroll
  for (int i = 0; i < 2; ++i) {
    int p  = (wave * 2 + i) * 1024 + lane * 16;  // byte pos in 32 KB tile
    int r  = p >> 8;                             // y row 0..127
    int pc = (p >> 4) & 15;                      // physical chunk
    int c  = pc ^ (r & 15);                      // logical chunk
    srcoff[i] = r * D_ + c * 8;                  // elements
    ldsoff[i] = (wave * 2 + i) * 1024;           // bytes (wave-uniform base)
  }

  // A fragments: direct global->register, rows n0 + wave*32 + rt*16 + l15.
  bf16x8 afrag[4][2];
  const size_t xrow0 = (size_t)b * N_ + n0 + wave * 32;
  #pragma unroll
  for (int kb = 0; kb < 4; ++kb)
    #pragma unroll
    for (int rt = 0; rt < 2; ++rt)
      afrag[kb][rt] = *(const bf16x8*)(xb + (xrow0 + rt * 16 + l15) * D_ + kb * 32 + quad * 8);

  // x2 for this wave's 8 output rows (block-constant)
  float xv[2][4];
  #pragma unroll
  for (int rt = 0; rt < 2; ++rt)
    #pragma unroll
    for (int r = 0; r < 4; ++r)
      xv[rt][r] = x2[(size_t)b * N_ + n0 + wave * 32 + rt * 16 + quad * 4 + r];

  const float FINF = __uint_as_float(0x7F800000u);
  float rmin2[2][4] = {{FINF, FINF, FINF, FINF}, {FINF, FINF, FINF, FINF}};

  // preload tile 0
  {
    const unsigned short* src = yb + ((size_t)b * M_ + mc0) * D_;
    gld16((char*)ys + ldsoff[0], src + srcoff[0]);
    gld16((char*)ys + ldsoff[1], src + srcoff[1]);
  }

  #pragma unroll 1
  for (int t = 0; t < TPB; ++t) {
    const int m0 = mc0 + t * 128;
    const int d  = (t & 1) * 32768;    // current buffer byte offset
    __syncthreads();  // (a): all waves drained own DMA vmcnt -> buf d ready; prior reads done

    // y2 loads BEFORE next DMA issue: older in vmcnt order, so consuming them
    // later leaves the prefetch DMAs in flight.
    float y2r[8];
    #pragma unroll
    for (int ct = 0; ct < 8; ++ct)
      y2r[ct] = y2[(size_t)b * M_ + m0 + ct * 16 + l15];

    if (t + 1 < TPB) {
      const unsigned short* src = yb + ((size_t)b * M_ + m0 + 128) * D_;
      char* dst = (char*)ys + (32768 - d);
      gld16(dst + ldsoff[0], src + srcoff[0]);
      gld16(dst + ldsoff[1], src + srcoff[1]);
    }

    f32x4 acc[2][8];
    #pragma unroll
    for (int rt = 0; rt < 2; ++rt)
      #pragma unroll
      for (int ct = 0; ct < 8; ++ct)
        acc[rt][ct] = (f32x4)(0.0f);

    #pragma unroll
    for (int kb = 0; kb < 4; ++kb) {
      #pragma unroll
      for (int ct = 0; ct < 8; ++ct) {
        const int row = ct * 16 + l15;
        const int pcB = (kb * 4 + quad) ^ l15;   // swizzled chunk
        bf16x8 bfr = *(const bf16x8*)((const char*)ys + d + row * 256 + pcB * 16);
        acc[0][ct] = __builtin_amdgcn_mfma_f32_16x16x32_bf16(afrag[kb][0], bfr, acc[0][ct], 0, 0, 0);
        acc[1][ct] = __builtin_amdgcn_mfma_f32_16x16x32_bf16(afrag[kb][1], bfr, acc[1][ct], 0, 0, 0);
      }
    }

    // Epilogue on d^2 = acc + x2_i + y2_j
    #pragma unroll
    for (int ct = 0; ct < 8; ++ct) {
      float yv = y2r[ct];
      float cm = FINF;
      #pragma unroll
      for (int rt = 0; rt < 2; ++rt) {
        #pragma unroll
        for (int r = 0; r < 4; ++r) {
          float s = acc[rt][ct][r] + xv[rt][r] + yv;
          rmin2[rt][r] = fminf(rmin2[rt][r], s);
          cm = fminf(cm, s);
        }
      }
      cm = fminf(cm, __shfl_xor(cm, 16, 64));
      cm = fminf(cm, __shfl_xor(cm, 32, 64));
      if (lane < 16) cminW[wave * 128 + ct * 16 + lane] = cm;  // plain write
    }
    __syncthreads();  // (b): cminW complete; also fences buf-d reads before next overwrite

    if (tid < 128) {
      float v = cminW[tid];
      #pragma unroll
      for (int w = 1; w < 16; ++w) v = fminf(v, cminW[w * 128 + tid]);
      colpart[(size_t)xg * (B_ * M_) + (size_t)b * M_ + m0 + tid] = v;
    }
  }

  // Row mins over this chunk: reduce across 16 col-lanes, store partial.
  #pragma unroll
  for (int rt = 0; rt < 2; ++rt) {
    #pragma unroll
    for (int r = 0; r < 4; ++r) {
      float v = rmin2[rt][r];
      v = fminf(v, __shfl_xor(v, 1, 64));
      v = fminf(v, __shfl_xor(v, 2, 64));
      v = fminf(v, __shfl_xor(v, 4, 64));
      v = fminf(v, __shfl_xor(v, 8, 64));
      if (l15 == 0)
        rowpart[(size_t)chunk * (B_ * N_) + (size_t)b * N_ + n0 + wave * 32 + rt * 16 + quad * 4 + r] = v;
    }
  }
}

// Pass 3: reduce partials (min over chunks/x-groups), sqrt, partial sums.
__global__ __launch_bounds__(256) void pass3_partial(
    const float* __restrict__ rowpart, const float* __restrict__ colpart,
    float* __restrict__ partial)
{
  const int BN = B_ * N_;
  float s1 = 0.0f, s2 = 0.0f;
  for (int i = blockIdx.x * 256 + threadIdx.x; i < BN; i += 64 * 256) {
    float r = rowpart[i];
    #pragma unroll
    for (int c = 1; c < CHUNKS; ++c) r = fminf(r, rowpart[c * BN + i]);
    s1 += sqrtf(fmaxf(r, 0.0f));
    float m = colpart[i];
    #pragma unroll
    for (int g = 1; g < XG; ++g) m = fminf(m, colpart[g * BN + i]);
    s2 += sqrtf(fmaxf(m, 0.0f));
  }
  #pragma unroll
  for (int m = 1; m < 64; m <<= 1) { s1 += __shfl_xor(s1, m, 64); s2 += __shfl_xor(s2, m, 64); }
  __shared__ float r1[4], r2[4];
  int wave = threadIdx.x >> 6, lane = threadIdx.x & 63;
  if (lane == 0) { r1[wave] = s1; r2[wave] = s2; }
  __syncthreads();
  if (threadIdx.x == 0) {
    partial[blockIdx.x]      = r1[0] + r1[1] + r1[2] + r1[3];
    partial[64 + blockIdx.x] = r2[0] + r2[1] + r2[2] + r2[3];
  }
}

// Pass 4: final 64->1 reduce, write scalar loss.
__global__ void pass4_final(const float* __restrict__ partial, float* __restrict__ out)
{
  int lane = threadIdx.x;
  float s = partial[lane] + partial[64 + lane];
  #pragma unroll
  for (int m = 1; m < 64; m <<= 1) s += __shfl_xor(s, m, 64);
  if (lane == 0) out[0] = s / (float)(B_ * N_);
}

extern "C" void kernel_launch(void* const* d_in, const int* in_sizes, int n_in,
                              void* d_out, int out_size, void* d_ws, size_t ws_size,
                              hipStream_t stream)
{
  const float* x = (const float*)d_in[0];
  const float* y = (const float*)d_in[1];
  char* ws = (char*)d_ws;

  unsigned short* xb = (unsigned short*)(ws);
  unsigned short* yb = (unsigned short*)(ws + (8u << 20));
  float* x2      = (float*)(ws + (16u << 20));
  float* y2      = (float*)(ws + (16u << 20) + (1u << 17));
  float* rowpart = (float*)(ws + (16u << 20) + (2u << 17));   // 4*B*N floats = 512 KB
  float* colpart = (float*)(ws + (16u << 20) + (6u << 17));   // 8*B*M floats = 1 MB
  float* partial = (float*)(ws + (16u << 20) + (14u << 17));
  float* outf = (float*)d_out;

  // 65536 rows, 2 rows per wave, 4 waves per block -> 8192 blocks.
  pass1_prep<<<(B_ * N_) / 4, 256, 0, stream>>>(x, y, xb, yb, x2, y2);

  pass2_tile<<<B_ * XG * CHUNKS, 1024, 0, stream>>>(xb, yb, x2, y2, rowpart, colpart);

  pass3_partial<<<64, 256, 0, stream>>>(rowpart, colpart, partial);
  pass4_final<<<1, 64, 0, stream>>>(partial, outf);
}

// Round 6
// 142.537 us; speedup vs baseline: 1.3236x; 1.2304x over previous
//
#include <hip/hip_runtime.h>
#include <cstdint>

// Chamfer distance, B=8, N=M=4096, D=128, f32 in, scalar f32 out.
// R6: kill the spill. R2-R5's launch_bounds 2nd arg acted as workgroups/CU
// (CUDA semantics) -> 64-VGPR cap -> accumulator scratch spills = the
// phantom ~190MB of FETCH+WRITE. Now __launch_bounds__(1024,1) (cap 128) +
// ct-outer/kb-inner loop so only 2 f32x4 accs are live (reg need ~95).
// Single barrier per tile (double-buffered col-min LDS), y prefetch DMA gets
// a full iteration in flight.
// Workspace: xb(8M) yb(8M) x2(128K) y2(128K) rowpart(512K) colpart(1M) partial.

#define B_   8
#define N_   4096
#define M_   4096
#define D_   128
#define TPB  8               // y-tiles (128 cols) per block
#define ROWS_PB 512          // x-rows per block = 16 waves * 32
#define XG   (N_ / ROWS_PB)  // 8 x-groups
#define CHUNKS (M_ / (TPB * 128))  // 4 y-chunks

typedef __bf16 bf16x8 __attribute__((ext_vector_type(8)));
typedef float  f32x4  __attribute__((ext_vector_type(4)));
typedef unsigned int u32;

static __device__ __forceinline__ unsigned short f2bf(float f) {
  unsigned u = __float_as_uint(f);
  u += 0x7FFFu + ((u >> 16) & 1u);   // round-to-nearest-even
  return (unsigned short)(u >> 16);
}

static __device__ __forceinline__ void gld16(void* lds, const void* g) {
  __builtin_amdgcn_global_load_lds(
      (const __attribute__((address_space(1))) void*)g,
      (__attribute__((address_space(3))) void*)lds, 16, 0, 0);
}

// Pass 1: wave handles 2 rows (32 lanes x float4 each). xb = bf16(-2x),
// yb = bf16(y), fp32 norms.
__global__ __launch_bounds__(256) void pass1_prep(
    const float* __restrict__ x, const float* __restrict__ y,
    unsigned short* __restrict__ xb, unsigned short* __restrict__ yb,
    float* __restrict__ x2, float* __restrict__ y2)
{
  const int ROWS = B_ * N_;
  int gw   = (blockIdx.x * 256 + threadIdx.x) >> 6;   // wave id
  int lane = threadIdx.x & 63;
  int half = lane >> 5, sub = lane & 31;
  int row2 = gw * 2 + half;                  // 0 .. 2*ROWS-1 (x rows then y rows)
  bool isx = row2 < ROWS;
  const float* src; unsigned short* dst; float* nrm; int row;
  if (isx) { src = x; dst = xb; nrm = x2; row = row2; }
  else     { src = y; dst = yb; nrm = y2; row = row2 - ROWS; }
  size_t base = (size_t)row * D_ + sub * 4;
  float4 v = *(const float4*)(src + base);
  float sx = isx ? -2.0f : 1.0f;
  u32 p0 = (u32)f2bf(sx * v.x) | ((u32)f2bf(sx * v.y) << 16);
  u32 p1 = (u32)f2bf(sx * v.z) | ((u32)f2bf(sx * v.w) << 16);
  *(uint2*)(dst + base) = make_uint2(p0, p1);
  float s = v.x * v.x + v.y * v.y + v.z * v.z + v.w * v.w;
  #pragma unroll
  for (int m = 1; m < 32; m <<= 1) s += __shfl_xor(s, m, 64);
  if (sub == 0) nrm[row] = s;
}

// Pass 2: block = 512 x-rows (16 waves x 32), loops over TPB y-tiles of 128
// cols. y staged by global_load_lds into XOR-swizzled LDS (row r, logical
// 16B-chunk c at physical chunk c^(r&15); rows 256 B, no padding).
// Fragment layouts (HW-verified):
//   A/B operand: lane holds elems [row=lane&15][k=(lane>>4)*8 + 0..7]
//   C/D:         lane reg r holds [row=(lane>>4)*4+r][col=lane&15]
// acc = -2<x,y>; epilogue s = acc + x2_i + y2_j = d^2; mins on d^2.
// ct-outer / kb-inner: only one (rt x f32x4) acc pair live at a time.
__global__ __launch_bounds__(1024, 1) void pass2_tile(
    const unsigned short* __restrict__ xb, const unsigned short* __restrict__ yb,
    const float* __restrict__ x2, const float* __restrict__ y2,
    float* __restrict__ rowpart, float* __restrict__ colpart)
{
  __shared__ unsigned short ys[2 * 16384];   // two 32 KB swizzled y-tiles
  __shared__ float cminW[2][16 * 128];       // double-buffered per-wave col mins

  const int tid  = threadIdx.x;
  const int wave = tid >> 6;
  const int lane = tid & 63;
  const int quad = lane >> 4;
  const int l15  = lane & 15;

  const int id    = blockIdx.x;        // 0..255
  const int b     = id & 7;
  const int j     = id >> 3;           // 0..31
  const int xg    = j & 7;
  const int chunk = j >> 3;            // 0..3
  const int n0    = xg * ROWS_PB;
  const int mc0   = chunk * (TPB * 128);

  // DMA lane offsets: instr i of wave w covers tile bytes (w*2+i)*1024+lane*16.
  int srcoff[2], ldsoff[2];
  #pragma unroll
  for (int i = 0; i < 2; ++i) {
    int p  = (wave * 2 + i) * 1024 + lane * 16;  // byte pos in 32 KB tile
    int r  = p >> 8;                             // y row 0..127
    int pc = (p >> 4) & 15;                      // physical chunk
    int c  = pc ^ (r & 15);                      // logical chunk
    srcoff[i] = r * D_ + c * 8;                  // elements
    ldsoff[i] = (wave * 2 + i) * 1024;           // bytes (wave-uniform base)
  }

  // A fragments: direct global->register, rows n0 + wave*32 + rt*16 + l15.
  bf16x8 afrag[4][2];
  const size_t xrow0 = (size_t)b * N_ + n0 + wave * 32;
  #pragma unroll
  for (int kb = 0; kb < 4; ++kb)
    #pragma unroll
    for (int rt = 0; rt < 2; ++rt)
      afrag[kb][rt] = *(const bf16x8*)(xb + (xrow0 + rt * 16 + l15) * D_ + kb * 32 + quad * 8);

  // x2 for this wave's 8 output rows (block-constant)
  float xv[2][4];
  #pragma unroll
  for (int rt = 0; rt < 2; ++rt)
    #pragma unroll
    for (int r = 0; r < 4; ++r)
      xv[rt][r] = x2[(size_t)b * N_ + n0 + wave * 32 + rt * 16 + quad * 4 + r];

  const float FINF = __uint_as_float(0x7F800000u);
  float rmin2[2][4] = {{FINF, FINF, FINF, FINF}, {FINF, FINF, FINF, FINF}};

  // preload tile 0
  {
    const unsigned short* src = yb + ((size_t)b * M_ + mc0) * D_;
    gld16((char*)ys + ldsoff[0], src + srcoff[0]);
    gld16((char*)ys + ldsoff[1], src + srcoff[1]);
  }

  #pragma unroll 1
  for (int t = 0; t < TPB; ++t) {
    const int m0 = mc0 + t * 128;
    const int d  = (t & 1) * 32768;    // current buffer byte offset
    __syncthreads();  // drains DMA for buf d (full prior iteration in flight);
                      // fences prior buf reads and cminW[(t-1)&1] writes

    float y2r[8];
    #pragma unroll
    for (int ct = 0; ct < 8; ++ct)
      y2r[ct] = y2[(size_t)b * M_ + m0 + ct * 16 + l15];

    if (t + 1 < TPB) {  // prefetch next tile into the other buffer
      const unsigned short* src = yb + ((size_t)b * M_ + m0 + 128) * D_;
      char* dst = (char*)ys + (32768 - d);
      gld16(dst + ldsoff[0], src + srcoff[0]);
      gld16(dst + ldsoff[1], src + srcoff[1]);
    }

    // Flush previous tile's column mins (reads cminW[(t-1)&1], other buffer
    // than this iteration's writes -> no race).
    if (t > 0 && tid < 128) {
      float v = cminW[(t - 1) & 1][tid];
      #pragma unroll
      for (int w = 1; w < 16; ++w) v = fminf(v, cminW[(t - 1) & 1][w * 128 + tid]);
      colpart[(size_t)xg * (B_ * M_) + (size_t)b * M_ + (m0 - 128) + tid] = v;
    }

    #pragma unroll
    for (int ct = 0; ct < 8; ++ct) {
      f32x4 a0 = (f32x4)(0.0f), a1 = (f32x4)(0.0f);
      #pragma unroll
      for (int kb = 0; kb < 4; ++kb) {
        const int row = ct * 16 + l15;
        const int pcB = (kb * 4 + quad) ^ l15;   // swizzled chunk
        bf16x8 bfr = *(const bf16x8*)((const char*)ys + d + row * 256 + pcB * 16);
        a0 = __builtin_amdgcn_mfma_f32_16x16x32_bf16(afrag[kb][0], bfr, a0, 0, 0, 0);
        a1 = __builtin_amdgcn_mfma_f32_16x16x32_bf16(afrag[kb][1], bfr, a1, 0, 0, 0);
      }
      float yv = y2r[ct];
      float cm = FINF;
      #pragma unroll
      for (int r = 0; r < 4; ++r) {
        float s0 = a0[r] + xv[0][r] + yv;
        float s1 = a1[r] + xv[1][r] + yv;
        rmin2[0][r] = fminf(rmin2[0][r], s0);
        rmin2[1][r] = fminf(rmin2[1][r], s1);
        cm = fminf(cm, fminf(s0, s1));
      }
      cm = fminf(cm, __shfl_xor(cm, 16, 64));
      cm = fminf(cm, __shfl_xor(cm, 32, 64));
      if (lane < 16) cminW[t & 1][wave * 128 + ct * 16 + lane] = cm;
    }
  }

  __syncthreads();  // final tile's cminW writes visible
  if (tid < 128) {
    float v = cminW[(TPB - 1) & 1][tid];
    #pragma unroll
    for (int w = 1; w < 16; ++w) v = fminf(v, cminW[(TPB - 1) & 1][w * 128 + tid]);
    colpart[(size_t)xg * (B_ * M_) + (size_t)b * M_ + (mc0 + (TPB - 1) * 128) + tid] = v;
  }

  // Row mins over this chunk: reduce across 16 col-lanes, store partial.
  #pragma unroll
  for (int rt = 0; rt < 2; ++rt) {
    #pragma unroll
    for (int r = 0; r < 4; ++r) {
      float v = rmin2[rt][r];
      v = fminf(v, __shfl_xor(v, 1, 64));
      v = fminf(v, __shfl_xor(v, 2, 64));
      v = fminf(v, __shfl_xor(v, 4, 64));
      v = fminf(v, __shfl_xor(v, 8, 64));
      if (l15 == 0)
        rowpart[(size_t)chunk * (B_ * N_) + (size_t)b * N_ + n0 + wave * 32 + rt * 16 + quad * 4 + r] = v;
    }
  }
}

// Pass 3: reduce partials (min over chunks/x-groups), sqrt, partial sums.
__global__ __launch_bounds__(256) void pass3_partial(
    const float* __restrict__ rowpart, const float* __restrict__ colpart,
    float* __restrict__ partial)
{
  const int BN = B_ * N_;
  float s1 = 0.0f, s2 = 0.0f;
  for (int i = blockIdx.x * 256 + threadIdx.x; i < BN; i += 64 * 256) {
    float r = rowpart[i];
    #pragma unroll
    for (int c = 1; c < CHUNKS; ++c) r = fminf(r, rowpart[c * BN + i]);
    s1 += sqrtf(fmaxf(r, 0.0f));
    float m = colpart[i];
    #pragma unroll
    for (int g = 1; g < XG; ++g) m = fminf(m, colpart[g * BN + i]);
    s2 += sqrtf(fmaxf(m, 0.0f));
  }
  #pragma unroll
  for (int m = 1; m < 64; m <<= 1) { s1 += __shfl_xor(s1, m, 64); s2 += __shfl_xor(s2, m, 64); }
  __shared__ float r1[4], r2[4];
  int wave = threadIdx.x >> 6, lane = threadIdx.x & 63;
  if (lane == 0) { r1[wave] = s1; r2[wave] = s2; }
  __syncthreads();
  if (threadIdx.x == 0) {
    partial[blockIdx.x]      = r1[0] + r1[1] + r1[2] + r1[3];
    partial[64 + blockIdx.x] = r2[0] + r2[1] + r2[2] + r2[3];
  }
}

// Pass 4: final 64->1 reduce, write scalar loss.
__global__ void pass4_final(const float* __restrict__ partial, float* __restrict__ out)
{
  int lane = threadIdx.x;
  float s = partial[lane] + partial[64 + lane];
  #pragma unroll
  for (int m = 1; m < 64; m <<= 1) s += __shfl_xor(s, m, 64);
  if (lane == 0) out[0] = s / (float)(B_ * N_);
}

extern "C" void kernel_launch(void* const* d_in, const int* in_sizes, int n_in,
                              void* d_out, int out_size, void* d_ws, size_t ws_size,
                              hipStream_t stream)
{
  const float* x = (const float*)d_in[0];
  const float* y = (const float*)d_in[1];
  char* ws = (char*)d_ws;

  unsigned short* xb = (unsigned short*)(ws);
  unsigned short* yb = (unsigned short*)(ws + (8u << 20));
  float* x2      = (float*)(ws + (16u << 20));
  float* y2      = (float*)(ws + (16u << 20) + (1u << 17));
  float* rowpart = (float*)(ws + (16u << 20) + (2u << 17));   // 4*B*N floats = 512 KB
  float* colpart = (float*)(ws + (16u << 20) + (6u << 17));   // 8*B*M floats = 1 MB
  float* partial = (float*)(ws + (16u << 20) + (14u << 17));
  float* outf = (float*)d_out;

  pass1_prep<<<(B_ * N_) / 4, 256, 0, stream>>>(x, y, xb, yb, x2, y2);

  pass2_tile<<<B_ * XG * CHUNKS, 1024, 0, stream>>>(xb, yb, x2, y2, rowpart, colpart);

  pass3_partial<<<64, 256, 0, stream>>>(rowpart, colpart, partial);
  pass4_final<<<1, 64, 0, stream>>>(partial, outf);
}

// Round 7
// 129.568 us; speedup vs baseline: 1.4561x; 1.1001x over previous
//
#include <hip/hip_runtime.h>
#include <cstdint>

// Chamfer distance, B=8, N=M=4096, D=128, f32 in, scalar f32 out.
// R7: pin VGPR budget. Evidence R1 vs R2-R6: any 2nd __launch_bounds__ arg
// -> allocator targets 8 waves/EU -> 64-VGPR cap -> scratch spills (~87MB
// phantom WRITE_SIZE). Now amdgpu_waves_per_eu(4,4) pins budget to 128 VGPRs
// (LDS 84KB already limits to 1 block/CU, so no occupancy loss). Also: chunk
// y^2 staged to LDS once (hot loop's only vmem = prefetch DMA).
// Workspace: xb(8M) yb(8M) x2(128K) y2(128K) rowpart(512K) colpart(1M) partial.

#define B_   8
#define N_   4096
#define M_   4096
#define D_   128
#define TPB  8               // y-tiles (128 cols) per block
#define ROWS_PB 512          // x-rows per block = 16 waves * 32
#define XG   (N_ / ROWS_PB)  // 8 x-groups
#define CHUNKS (M_ / (TPB * 128))  // 4 y-chunks

typedef __bf16 bf16x8 __attribute__((ext_vector_type(8)));
typedef float  f32x4  __attribute__((ext_vector_type(4)));
typedef unsigned int u32;

static __device__ __forceinline__ unsigned short f2bf(float f) {
  unsigned u = __float_as_uint(f);
  u += 0x7FFFu + ((u >> 16) & 1u);   // round-to-nearest-even
  return (unsigned short)(u >> 16);
}

static __device__ __forceinline__ void gld16(void* lds, const void* g) {
  __builtin_amdgcn_global_load_lds(
      (const __attribute__((address_space(1))) void*)g,
      (__attribute__((address_space(3))) void*)lds, 16, 0, 0);
}

// Pass 1: wave handles 2 rows (32 lanes x float4 each). xb = bf16(-2x),
// yb = bf16(y), fp32 norms.
__global__ __launch_bounds__(256) void pass1_prep(
    const float* __restrict__ x, const float* __restrict__ y,
    unsigned short* __restrict__ xb, unsigned short* __restrict__ yb,
    float* __restrict__ x2, float* __restrict__ y2)
{
  const int ROWS = B_ * N_;
  int gw   = (blockIdx.x * 256 + threadIdx.x) >> 6;   // wave id
  int lane = threadIdx.x & 63;
  int half = lane >> 5, sub = lane & 31;
  int row2 = gw * 2 + half;                  // 0 .. 2*ROWS-1 (x rows then y rows)
  bool isx = row2 < ROWS;
  const float* src; unsigned short* dst; float* nrm; int row;
  if (isx) { src = x; dst = xb; nrm = x2; row = row2; }
  else     { src = y; dst = yb; nrm = y2; row = row2 - ROWS; }
  size_t base = (size_t)row * D_ + sub * 4;
  float4 v = *(const float4*)(src + base);
  float sx = isx ? -2.0f : 1.0f;
  u32 p0 = (u32)f2bf(sx * v.x) | ((u32)f2bf(sx * v.y) << 16);
  u32 p1 = (u32)f2bf(sx * v.z) | ((u32)f2bf(sx * v.w) << 16);
  *(uint2*)(dst + base) = make_uint2(p0, p1);
  float s = v.x * v.x + v.y * v.y + v.z * v.z + v.w * v.w;
  #pragma unroll
  for (int m = 1; m < 32; m <<= 1) s += __shfl_xor(s, m, 64);
  if (sub == 0) nrm[row] = s;
}

// Pass 2: block = 512 x-rows (16 waves x 32), loops over TPB y-tiles of 128
// cols. y staged by global_load_lds into XOR-swizzled LDS (row r, logical
// 16B-chunk c at physical chunk c^(r&15); rows 256 B, no padding).
// Fragment layouts (HW-verified):
//   A/B operand: lane holds elems [row=lane&15][k=(lane>>4)*8 + 0..7]
//   C/D:         lane reg r holds [row=(lane>>4)*4+r][col=lane&15]
// acc = -2<x,y>; epilogue s = acc + x2_i + y2_j = d^2; mins on d^2.
__global__
__attribute__((amdgpu_waves_per_eu(4, 4)))   // pin 4 waves/EU -> 128-VGPR budget, no spills
__launch_bounds__(1024)
void pass2_tile(
    const unsigned short* __restrict__ xb, const unsigned short* __restrict__ yb,
    const float* __restrict__ x2, const float* __restrict__ y2,
    float* __restrict__ rowpart, float* __restrict__ colpart)
{
  __shared__ unsigned short ys[2 * 16384];   // two 32 KB swizzled y-tiles
  __shared__ float cminW[2][16 * 128];       // double-buffered per-wave col mins
  __shared__ float y2s[TPB * 128];           // whole chunk's y^2 (4 KB)

  const int tid  = threadIdx.x;
  const int wave = tid >> 6;
  const int lane = tid & 63;
  const int quad = lane >> 4;
  const int l15  = lane & 15;

  const int id    = blockIdx.x;        // 0..255
  const int b     = id & 7;
  const int j     = id >> 3;           // 0..31
  const int xg    = j & 7;
  const int chunk = j >> 3;            // 0..3
  const int n0    = xg * ROWS_PB;
  const int mc0   = chunk * (TPB * 128);

  // DMA lane offsets: instr i of wave w covers tile bytes (w*2+i)*1024+lane*16.
  int srcoff[2], ldsoff[2];
  #pragma unroll
  for (int i = 0; i < 2; ++i) {
    int p  = (wave * 2 + i) * 1024 + lane * 16;  // byte pos in 32 KB tile
    int r  = p >> 8;                             // y row 0..127
    int pc = (p >> 4) & 15;                      // physical chunk
    int c  = pc ^ (r & 15);                      // logical chunk
    srcoff[i] = r * D_ + c * 8;                  // elements
    ldsoff[i] = (wave * 2 + i) * 1024;           // bytes (wave-uniform base)
  }

  // preload tile 0 + whole-chunk y2 into LDS
  {
    const unsigned short* src = yb + ((size_t)b * M_ + mc0) * D_;
    gld16((char*)ys + ldsoff[0], src + srcoff[0]);
    gld16((char*)ys + ldsoff[1], src + srcoff[1]);
  }
  y2s[tid] = y2[(size_t)b * M_ + mc0 + tid];

  // A fragments: direct global->register, rows n0 + wave*32 + rt*16 + l15.
  bf16x8 afrag[4][2];
  const size_t xrow0 = (size_t)b * N_ + n0 + wave * 32;
  #pragma unroll
  for (int kb = 0; kb < 4; ++kb)
    #pragma unroll
    for (int rt = 0; rt < 2; ++rt)
      afrag[kb][rt] = *(const bf16x8*)(xb + (xrow0 + rt * 16 + l15) * D_ + kb * 32 + quad * 8);

  // x2 for this wave's 8 output rows (block-constant)
  float xv[2][4];
  #pragma unroll
  for (int rt = 0; rt < 2; ++rt)
    #pragma unroll
    for (int r = 0; r < 4; ++r)
      xv[rt][r] = x2[(size_t)b * N_ + n0 + wave * 32 + rt * 16 + quad * 4 + r];

  const float FINF = __uint_as_float(0x7F800000u);
  float rmin2[2][4] = {{FINF, FINF, FINF, FINF}, {FINF, FINF, FINF, FINF}};

  #pragma unroll 1
  for (int t = 0; t < TPB; ++t) {
    const int m0 = mc0 + t * 128;
    const int d  = (t & 1) * 32768;    // current buffer byte offset
    __syncthreads();  // drains DMA for buf d (prefetch had a full iteration);
                      // fences prior buf reads and cminW[(t-1)&1] writes

    if (t + 1 < TPB) {  // prefetch next tile into the other buffer
      const unsigned short* src = yb + ((size_t)b * M_ + m0 + 128) * D_;
      char* dst = (char*)ys + (32768 - d);
      gld16(dst + ldsoff[0], src + srcoff[0]);
      gld16(dst + ldsoff[1], src + srcoff[1]);
    }

    // Flush previous tile's column mins (other cminW buffer -> no race).
    if (t > 0 && tid < 128) {
      float v = cminW[(t - 1) & 1][tid];
      #pragma unroll
      for (int w = 1; w < 16; ++w) v = fminf(v, cminW[(t - 1) & 1][w * 128 + tid]);
      colpart[(size_t)xg * (B_ * M_) + (size_t)b * M_ + (m0 - 128) + tid] = v;
    }

    #pragma unroll
    for (int ct = 0; ct < 8; ++ct) {
      f32x4 a0 = (f32x4)(0.0f), a1 = (f32x4)(0.0f);
      #pragma unroll
      for (int kb = 0; kb < 4; ++kb) {
        const int row = ct * 16 + l15;
        const int pcB = (kb * 4 + quad) ^ l15;   // swizzled chunk
        bf16x8 bfr = *(const bf16x8*)((const char*)ys + d + row * 256 + pcB * 16);
        a0 = __builtin_amdgcn_mfma_f32_16x16x32_bf16(afrag[kb][0], bfr, a0, 0, 0, 0);
        a1 = __builtin_amdgcn_mfma_f32_16x16x32_bf16(afrag[kb][1], bfr, a1, 0, 0, 0);
      }
      float yv = y2s[t * 128 + ct * 16 + l15];  // quads share addr -> broadcast
      float cm = FINF;
      #pragma unroll
      for (int r = 0; r < 4; ++r) {
        float s0 = a0[r] + xv[0][r] + yv;
        float s1 = a1[r] + xv[1][r] + yv;
        rmin2[0][r] = fminf(rmin2[0][r], s0);
        rmin2[1][r] = fminf(rmin2[1][r], s1);
        cm = fminf(cm, fminf(s0, s1));
      }
      cm = fminf(cm, __shfl_xor(cm, 16, 64));
      cm = fminf(cm, __shfl_xor(cm, 32, 64));
      if (lane < 16) cminW[t & 1][wave * 128 + ct * 16 + lane] = cm;
    }
  }

  __syncthreads();  // final tile's cminW writes visible
  if (tid < 128) {
    float v = cminW[(TPB - 1) & 1][tid];
    #pragma unroll
    for (int w = 1; w < 16; ++w) v = fminf(v, cminW[(TPB - 1) & 1][w * 128 + tid]);
    colpart[(size_t)xg * (B_ * M_) + (size_t)b * M_ + (mc0 + (TPB - 1) * 128) + tid] = v;
  }

  // Row mins over this chunk: reduce across 16 col-lanes, store partial.
  #pragma unroll
  for (int rt = 0; rt < 2; ++rt) {
    #pragma unroll
    for (int r = 0; r < 4; ++r) {
      float v = rmin2[rt][r];
      v = fminf(v, __shfl_xor(v, 1, 64));
      v = fminf(v, __shfl_xor(v, 2, 64));
      v = fminf(v, __shfl_xor(v, 4, 64));
      v = fminf(v, __shfl_xor(v, 8, 64));
      if (l15 == 0)
        rowpart[(size_t)chunk * (B_ * N_) + (size_t)b * N_ + n0 + wave * 32 + rt * 16 + quad * 4 + r] = v;
    }
  }
}

// Pass 3: reduce partials (min over chunks/x-groups), sqrt, partial sums.
__global__ __launch_bounds__(256) void pass3_partial(
    const float* __restrict__ rowpart, const float* __restrict__ colpart,
    float* __restrict__ partial)
{
  const int BN = B_ * N_;
  float s1 = 0.0f, s2 = 0.0f;
  for (int i = blockIdx.x * 256 + threadIdx.x; i < BN; i += 64 * 256) {
    float r = rowpart[i];
    #pragma unroll
    for (int c = 1; c < CHUNKS; ++c) r = fminf(r, rowpart[c * BN + i]);
    s1 += sqrtf(fmaxf(r, 0.0f));
    float m = colpart[i];
    #pragma unroll
    for (int g = 1; g < XG; ++g) m = fminf(m, colpart[g * BN + i]);
    s2 += sqrtf(fmaxf(m, 0.0f));
  }
  #pragma unroll
  for (int m = 1; m < 64; m <<= 1) { s1 += __shfl_xor(s1, m, 64); s2 += __shfl_xor(s2, m, 64); }
  __shared__ float r1[4], r2[4];
  int wave = threadIdx.x >> 6, lane = threadIdx.x & 63;
  if (lane == 0) { r1[wave] = s1; r2[wave] = s2; }
  __syncthreads();
  if (threadIdx.x == 0) {
    partial[blockIdx.x]      = r1[0] + r1[1] + r1[2] + r1[3];
    partial[64 + blockIdx.x] = r2[0] + r2[1] + r2[2] + r2[3];
  }
}

// Pass 4: final 64->1 reduce, write scalar loss.
__global__ void pass4_final(const float* __restrict__ partial, float* __restrict__ out)
{
  int lane = threadIdx.x;
  float s = partial[lane] + partial[64 + lane];
  #pragma unroll
  for (int m = 1; m < 64; m <<= 1) s += __shfl_xor(s, m, 64);
  if (lane == 0) out[0] = s / (float)(B_ * N_);
}

extern "C" void kernel_launch(void* const* d_in, const int* in_sizes, int n_in,
                              void* d_out, int out_size, void* d_ws, size_t ws_size,
                              hipStream_t stream)
{
  const float* x = (const float*)d_in[0];
  const float* y = (const float*)d_in[1];
  char* ws = (char*)d_ws;

  unsigned short* xb = (unsigned short*)(ws);
  unsigned short* yb = (unsigned short*)(ws + (8u << 20));
  float* x2      = (float*)(ws + (16u << 20));
  float* y2      = (float*)(ws + (16u << 20) + (1u << 17));
  float* rowpart = (float*)(ws + (16u << 20) + (2u << 17));   // 4*B*N floats = 512 KB
  float* colpart = (float*)(ws + (16u << 20) + (6u << 17));   // 8*B*M floats = 1 MB
  float* partial = (float*)(ws + (16u << 20) + (14u << 17));
  float* outf = (float*)d_out;

  pass1_prep<<<(B_ * N_) / 4, 256, 0, stream>>>(x, y, xb, yb, x2, y2);

  pass2_tile<<<B_ * XG * CHUNKS, 1024, 0, stream>>>(xb, yb, x2, y2, rowpart, colpart);

  pass3_partial<<<64, 256, 0, stream>>>(rowpart, colpart, partial);
  pass4_final<<<1, 64, 0, stream>>>(partial, outf);
}

// Round 8
// 122.135 us; speedup vs baseline: 1.5447x; 1.0609x over previous
//
#include <hip/hip_runtime.h>
#include <cstdint>

// Chamfer distance, B=8, N=M=4096, D=128, f32 in, scalar f32 out.
// R8: 512-thr blocks (8 waves x 64 x-rows, rt=4) to halve per-MFMA LDS
// B-traffic and escape the 1024-thr 64-VGPR allocator cap (R1 precedent:
// 256-thr+LB(256) -> 132 VGPRs). Block = 512 rows x 1024-col y-chunk,
// 256 blocks = 1/CU. y DMA-staged (XOR-16 swizzle, dbuf), A in registers.
// Workspace: xb(8M) yb(8M) x2(128K) y2(128K) rowpart(512K) colpart(1M) partial.

#define B_   8
#define N_   4096
#define M_   4096
#define D_   128
#define TPB  8               // y-tiles (128 cols) per block
#define ROWS_PB 512          // x-rows per block = 8 waves * 64
#define XG   (N_ / ROWS_PB)  // 8 x-groups
#define CHUNKS (M_ / (TPB * 128))  // 4 y-chunks

typedef __bf16 bf16x8 __attribute__((ext_vector_type(8)));
typedef float  f32x4  __attribute__((ext_vector_type(4)));
typedef unsigned int u32;

static __device__ __forceinline__ unsigned short f2bf(float f) {
  unsigned u = __float_as_uint(f);
  u += 0x7FFFu + ((u >> 16) & 1u);   // round-to-nearest-even
  return (unsigned short)(u >> 16);
}

static __device__ __forceinline__ void gld16(void* lds, const void* g) {
  __builtin_amdgcn_global_load_lds(
      (const __attribute__((address_space(1))) void*)g,
      (__attribute__((address_space(3))) void*)lds, 16, 0, 0);
}

// Pass 1: wave handles 2 rows (32 lanes x float4 each). xb = bf16(-2x),
// yb = bf16(y), fp32 norms.
__global__ __launch_bounds__(256) void pass1_prep(
    const float* __restrict__ x, const float* __restrict__ y,
    unsigned short* __restrict__ xb, unsigned short* __restrict__ yb,
    float* __restrict__ x2, float* __restrict__ y2)
{
  const int ROWS = B_ * N_;
  int gw   = (blockIdx.x * 256 + threadIdx.x) >> 6;   // wave id
  int lane = threadIdx.x & 63;
  int half = lane >> 5, sub = lane & 31;
  int row2 = gw * 2 + half;                  // 0 .. 2*ROWS-1 (x rows then y rows)
  bool isx = row2 < ROWS;
  const float* src; unsigned short* dst; float* nrm; int row;
  if (isx) { src = x; dst = xb; nrm = x2; row = row2; }
  else     { src = y; dst = yb; nrm = y2; row = row2 - ROWS; }
  size_t base = (size_t)row * D_ + sub * 4;
  float4 v = *(const float4*)(src + base);
  float sx = isx ? -2.0f : 1.0f;
  u32 p0 = (u32)f2bf(sx * v.x) | ((u32)f2bf(sx * v.y) << 16);
  u32 p1 = (u32)f2bf(sx * v.z) | ((u32)f2bf(sx * v.w) << 16);
  *(uint2*)(dst + base) = make_uint2(p0, p1);
  float s = v.x * v.x + v.y * v.y + v.z * v.z + v.w * v.w;
  #pragma unroll
  for (int m = 1; m < 32; m <<= 1) s += __shfl_xor(s, m, 64);
  if (sub == 0) nrm[row] = s;
}

// Pass 2: block = 512 x-rows (8 waves x 64 rows = 4 row-tiles of 16), loops
// over TPB y-tiles of 128 cols. y staged by global_load_lds into XOR-swizzled
// LDS (row r, logical 16B-chunk c at physical chunk c^(r&15); 256 B rows).
// Fragment layouts (HW-verified):
//   A/B operand: lane holds elems [row=lane&15][k=(lane>>4)*8 + 0..7]
//   C/D:         lane reg r holds [row=(lane>>4)*4+r][col=lane&15]
// acc = -2<x,y>; epilogue s = acc + x2_i + y2_j = d^2; mins on d^2.
// One ds_read_b128 B-frag feeds 4 MFMAs (rt=4) -> LDS floor halved vs R7.
__global__
__launch_bounds__(512)
__attribute__((amdgpu_waves_per_eu(2)))   // budget 256 VGPRs; kernel needs ~135
void pass2_tile(
    const unsigned short* __restrict__ xb, const unsigned short* __restrict__ yb,
    const float* __restrict__ x2, const float* __restrict__ y2,
    float* __restrict__ rowpart, float* __restrict__ colpart)
{
  __shared__ unsigned short ys[2 * 16384];   // two 32 KB swizzled y-tiles
  __shared__ float cminW[2][8 * 128];        // double-buffered per-wave col mins
  __shared__ float y2s[TPB * 128];           // whole chunk's y^2 (4 KB)

  const int tid  = threadIdx.x;
  const int wave = tid >> 6;                 // 0..7
  const int lane = tid & 63;
  const int quad = lane >> 4;
  const int l15  = lane & 15;

  const int id    = blockIdx.x;        // 0..255
  const int b     = id & 7;
  const int j     = id >> 3;           // 0..31
  const int xg    = j & 7;
  const int chunk = j >> 3;            // 0..3
  const int n0    = xg * ROWS_PB;
  const int mc0   = chunk * (TPB * 128);

  // preload tile 0 (4 gld16 per wave: instr i covers tile bytes
  // (wave*4+i)*1024 + lane*16) + whole-chunk y2 into LDS.
  {
    const unsigned short* src = yb + ((size_t)b * M_ + mc0) * D_;
    #pragma unroll
    for (int i = 0; i < 4; ++i) {
      int p  = (wave * 4 + i) * 1024 + lane * 16;
      int r  = p >> 8;
      int pc = (p >> 4) & 15;
      int c  = pc ^ (r & 15);
      gld16((char*)ys + (wave * 4 + i) * 1024, src + r * D_ + c * 8);
    }
  }
  y2s[tid]       = y2[(size_t)b * M_ + mc0 + tid];
  y2s[tid + 512] = y2[(size_t)b * M_ + mc0 + tid + 512];

  // A fragments: direct global->register, rows n0 + wave*64 + rt*16 + l15.
  bf16x8 afrag[4][4];   // [kb][rt]
  const size_t xrow0 = (size_t)b * N_ + n0 + wave * 64;
  #pragma unroll
  for (int kb = 0; kb < 4; ++kb)
    #pragma unroll
    for (int rt = 0; rt < 4; ++rt)
      afrag[kb][rt] = *(const bf16x8*)(xb + (xrow0 + rt * 16 + l15) * D_ + kb * 32 + quad * 8);

  // x2 for this wave's 16 output rows (t-invariant)
  float xv[4][4];
  #pragma unroll
  for (int rt = 0; rt < 4; ++rt)
    #pragma unroll
    for (int r = 0; r < 4; ++r)
      xv[rt][r] = x2[(size_t)b * N_ + n0 + wave * 64 + rt * 16 + quad * 4 + r];

  const float FINF = __uint_as_float(0x7F800000u);
  float rmin2[4][4];
  #pragma unroll
  for (int rt = 0; rt < 4; ++rt)
    #pragma unroll
    for (int r = 0; r < 4; ++r) rmin2[rt][r] = FINF;

  #pragma unroll 1
  for (int t = 0; t < TPB; ++t) {
    const int m0 = mc0 + t * 128;
    const int d  = (t & 1) * 32768;    // current buffer byte offset
    __syncthreads();  // drains DMA for buf d (prefetch had a full iteration);
                      // fences prior buf reads and cminW[(t-1)&1] writes

    if (t + 1 < TPB) {  // prefetch next tile into the other buffer
      const unsigned short* src = yb + ((size_t)b * M_ + m0 + 128) * D_;
      char* dst = (char*)ys + (32768 - d);
      #pragma unroll
      for (int i = 0; i < 4; ++i) {
        int p  = (wave * 4 + i) * 1024 + lane * 16;
        int r  = p >> 8;
        int pc = (p >> 4) & 15;
        int c  = pc ^ (r & 15);
        gld16(dst + (wave * 4 + i) * 1024, src + r * D_ + c * 8);
      }
    }

    // Flush previous tile's column mins (other cminW buffer -> no race).
    if (t > 0 && tid < 128) {
      float v = cminW[(t - 1) & 1][tid];
      #pragma unroll
      for (int w = 1; w < 8; ++w) v = fminf(v, cminW[(t - 1) & 1][w * 128 + tid]);
      colpart[(size_t)xg * (B_ * M_) + (size_t)b * M_ + (m0 - 128) + tid] = v;
    }

    #pragma unroll
    for (int ct = 0; ct < 8; ++ct) {
      f32x4 a[4];
      #pragma unroll
      for (int rt = 0; rt < 4; ++rt) a[rt] = (f32x4)(0.0f);
      #pragma unroll
      for (int kb = 0; kb < 4; ++kb) {
        const int row = ct * 16 + l15;
        const int pcB = (kb * 4 + quad) ^ l15;   // swizzled chunk
        bf16x8 bfr = *(const bf16x8*)((const char*)ys + d + row * 256 + pcB * 16);
        #pragma unroll
        for (int rt = 0; rt < 4; ++rt)
          a[rt] = __builtin_amdgcn_mfma_f32_16x16x32_bf16(afrag[kb][rt], bfr, a[rt], 0, 0, 0);
      }
      float yv = y2s[t * 128 + ct * 16 + l15];  // quads share addr -> broadcast
      float cm = FINF;
      #pragma unroll
      for (int rt = 0; rt < 4; ++rt) {
        #pragma unroll
        for (int r = 0; r < 4; ++r) {
          float s = a[rt][r] + xv[rt][r] + yv;
          rmin2[rt][r] = fminf(rmin2[rt][r], s);
          cm = fminf(cm, s);
        }
      }
      cm = fminf(cm, __shfl_xor(cm, 16, 64));
      cm = fminf(cm, __shfl_xor(cm, 32, 64));
      if (lane < 16) cminW[t & 1][wave * 128 + ct * 16 + lane] = cm;
    }
  }

  __syncthreads();  // final tile's cminW writes visible
  if (tid < 128) {
    float v = cminW[(TPB - 1) & 1][tid];
    #pragma unroll
    for (int w = 1; w < 8; ++w) v = fminf(v, cminW[(TPB - 1) & 1][w * 128 + tid]);
    colpart[(size_t)xg * (B_ * M_) + (size_t)b * M_ + (mc0 + (TPB - 1) * 128) + tid] = v;
  }

  // Row mins over this chunk: reduce across 16 col-lanes, store partial.
  #pragma unroll
  for (int rt = 0; rt < 4; ++rt) {
    #pragma unroll
    for (int r = 0; r < 4; ++r) {
      float v = rmin2[rt][r];
      v = fminf(v, __shfl_xor(v, 1, 64));
      v = fminf(v, __shfl_xor(v, 2, 64));
      v = fminf(v, __shfl_xor(v, 4, 64));
      v = fminf(v, __shfl_xor(v, 8, 64));
      if (l15 == 0)
        rowpart[(size_t)chunk * (B_ * N_) + (size_t)b * N_ + n0 + wave * 64 + rt * 16 + quad * 4 + r] = v;
    }
  }
}

// Pass 3: reduce partials (min over chunks/x-groups), sqrt, partial sums.
__global__ __launch_bounds__(256) void pass3_partial(
    const float* __restrict__ rowpart, const float* __restrict__ colpart,
    float* __restrict__ partial)
{
  const int BN = B_ * N_;
  float s1 = 0.0f, s2 = 0.0f;
  for (int i = blockIdx.x * 256 + threadIdx.x; i < BN; i += 64 * 256) {
    float r = rowpart[i];
    #pragma unroll
    for (int c = 1; c < CHUNKS; ++c) r = fminf(r, rowpart[c * BN + i]);
    s1 += sqrtf(fmaxf(r, 0.0f));
    float m = colpart[i];
    #pragma unroll
    for (int g = 1; g < XG; ++g) m = fminf(m, colpart[g * BN + i]);
    s2 += sqrtf(fmaxf(m, 0.0f));
  }
  #pragma unroll
  for (int m = 1; m < 64; m <<= 1) { s1 += __shfl_xor(s1, m, 64); s2 += __shfl_xor(s2, m, 64); }
  __shared__ float r1[4], r2[4];
  int wave = threadIdx.x >> 6, lane = threadIdx.x & 63;
  if (lane == 0) { r1[wave] = s1; r2[wave] = s2; }
  __syncthreads();
  if (threadIdx.x == 0) {
    partial[blockIdx.x]      = r1[0] + r1[1] + r1[2] + r1[3];
    partial[64 + blockIdx.x] = r2[0] + r2[1] + r2[2] + r2[3];
  }
}

// Pass 4: final 64->1 reduce, write scalar loss.
__global__ void pass4_final(const float* __restrict__ partial, float* __restrict__ out)
{
  int lane = threadIdx.x;
  float s = partial[lane] + partial[64 + lane];
  #pragma unroll
  for (int m = 1; m < 64; m <<= 1) s += __shfl_xor(s, m, 64);
  if (lane == 0) out[0] = s / (float)(B_ * N_);
}

extern "C" void kernel_launch(void* const* d_in, const int* in_sizes, int n_in,
                              void* d_out, int out_size, void* d_ws, size_t ws_size,
                              hipStream_t stream)
{
  const float* x = (const float*)d_in[0];
  const float* y = (const float*)d_in[1];
  char* ws = (char*)d_ws;

  unsigned short* xb = (unsigned short*)(ws);
  unsigned short* yb = (unsigned short*)(ws + (8u << 20));
  float* x2      = (float*)(ws + (16u << 20));
  float* y2      = (float*)(ws + (16u << 20) + (1u << 17));
  float* rowpart = (float*)(ws + (16u << 20) + (2u << 17));   // 4*B*N floats = 512 KB
  float* colpart = (float*)(ws + (16u << 20) + (6u << 17));   // 8*B*M floats = 1 MB
  float* partial = (float*)(ws + (16u << 20) + (14u << 17));
  float* outf = (float*)d_out;

  pass1_prep<<<(B_ * N_) / 4, 256, 0, stream>>>(x, y, xb, yb, x2, y2);

  pass2_tile<<<B_ * XG * CHUNKS, 512, 0, stream>>>(xb, yb, x2, y2, rowpart, colpart);

  pass3_partial<<<64, 256, 0, stream>>>(rowpart, colpart, partial);
  pass4_final<<<1, 64, 0, stream>>>(partial, outf);
}